// Round 9
// baseline (205.434 us; speedup 1.0000x reference)
//
#include <hip/hip_runtime.h>

// ElectronGNN on MI355X (gfx950).  Inputs float32, output float32.
// Round 9: occupancy-doubled design (16 waves/CU, was 8).
//   512 blocks x 512 threads, 1 batch/block, 2 blocks/CU (LDS 67,584 B).
//   8 waves = 4 row-tiles x 2 N-halves; each wave: 16 rows x 64 cols (4 acc tiles).
//   Single 32KB weight buffer; reg-prefetch staging one seg ahead
//   (consume order W0,W1,Y,W2,W3 so zst write->read pairs straddle barriers).
//   __launch_bounds__(512,4) caps VGPR at 128 -> 4 waves/SIMD.
// z B-frags: per-lane v_pk_mul_f16 recompute (r4/r7/r8-proven).
// zst is wave-PAIR shared (N-split): every write/read separated by a barrier.
// d_ws: 491,520 B (r7-proven).  Prep unchanged (r7-proven).

typedef unsigned short u16;
typedef unsigned int u32;
typedef __attribute__((ext_vector_type(8))) short short8;
typedef __attribute__((ext_vector_type(4))) float f32x4;
typedef __attribute__((ext_vector_type(4))) u32 u32x4;
typedef _Float16 h2 __attribute__((ext_vector_type(2)));

__device__ __forceinline__ u16 f2h(float f){ return __builtin_bit_cast(u16, (_Float16)f); }
__device__ __forceinline__ float h2f(u16 a){ return (float)__builtin_bit_cast(_Float16, a); }

__device__ __forceinline__ short8 rbf8(float dd){
  short8 a;
#pragma unroll
  for (int f = 0; f < 8; f++){
    float u = dd - (4.0f/7.0f)*(float)f;
    a[f] = (short)f2h(__expf(-u*u));
  }
  return a;
}

// ---------------- prep: frag-linear weight slabs (r7-proven, unchanged) ----------------
__global__ __launch_bounds__(256) void gnn_prep(
    const float* __restrict__ w_up, const float* __restrict__ we_ne,
    const float* __restrict__ embed, const int* __restrict__ atypes,
    u16* __restrict__ wsegs){
  __shared__ u16 lw[16384];
  const int blk = blockIdx.x;          // l*5 + seg
  const int l = blk / 5, seg = blk % 5;
  const int tid = threadIdx.x;
  if (seg < 4){
    const float* src = w_up + (l*512 + seg*128)*128;
#pragma unroll
    for (int mm = 0; mm < 16; mm++){
      int idx = mm*1024 + tid*4;
      float4 v = *(const float4*)(src + idx);
      lw[idx+0] = f2h(v.x); lw[idx+1] = f2h(v.y);
      lw[idx+2] = f2h(v.z); lw[idx+3] = f2h(v.w);
    }
  } else {
#pragma unroll
    for (int mm = 0; mm < 16; mm++){
      int idx = mm*1024 + tid*4;
      int k = idx >> 7, dout = idx & 127;
      int n = k >> 3, f = k & 7;
      float4 ye = *(const float4*)(embed + atypes[n]*128 + dout);
      float4 wn = *(const float4*)(we_ne + (l*8 + f)*128 + dout);
      lw[idx+0] = f2h(ye.x*wn.x); lw[idx+1] = f2h(ye.y*wn.y);
      lw[idx+2] = f2h(ye.z*wn.z); lw[idx+3] = f2h(ye.w*wn.w);
    }
  }
  __syncthreads();
  u16* dst = wsegs + blk*16384;
  const int col = tid & 15, q = (tid >> 4) & 3;
#pragma unroll
  for (int m = 0; m < 8; m++){
    int slot = m*4 + (tid >> 6);
    int c = slot >> 3, nt = slot & 7;
    int kbase = c*32 + q*8;
    int dout = nt*16 + col;
    short8 vv;
#pragma unroll
    for (int jj = 0; jj < 8; jj++) vv[jj] = (short)lw[(kbase+jj)*128 + dout];
    *(short8*)(dst + m*2048 + tid*8) = vv;
  }
}

// ---------------- main ----------------
__global__ __launch_bounds__(512, 4) void gnn_main(
    const float* __restrict__ r_g, const float* __restrict__ R_g,
    const float* __restrict__ weS_g, const float* __restrict__ weA_g,
    const float* __restrict__ bup_g,
    const u16* __restrict__ wsegs,
    float* __restrict__ out)
{
  extern __shared__ __attribute__((aligned(16))) u16 lds[];
  u16* const wbuf = lds;                 // 16384 u16 (32 KB)
  u16* const xb   = lds + 16384;         // [64][136]
  u16* const zst  = lds + 16384 + 8704;  // [64][136]

  const int tid  = threadIdx.x;
  const int b    = blockIdx.x;
  const int lane = tid & 63;
  const int w    = tid >> 6;            // 0..7
  const int wq   = w & 3;               // row tile
  const int nh   = w >> 2;              // N half 0/1
  const int col  = lane & 15;
  const int q    = lane >> 4;
  const int i0   = wq * 16;
  const int sp   = wq >> 1;
  const int mrow = i0 + col;
  const int loff = (q*16 + col) * 8;
  const int ntb  = nh * 4;              // nt base for this wave

  u32x4 stg[4];
  auto stg_ld = [&](const u16* src){
#pragma unroll
    for (int m = 0; m < 4; m++) stg[m] = *(const u32x4*)(src + m*4096 + tid*8);
  };
  auto stg_st = [&](){
#pragma unroll
    for (int m = 0; m < 4; m++) *(u32x4*)(wbuf + m*4096 + tid*8) = stg[m];
  };
  // 4-chunk x 4-tile GEMM against current wbuf seg
  auto gemm4 = [&](const u16* arows, f32x4* acc){
#pragma unroll
    for (int c = 0; c < 4; c++){
      short8 a = *(const short8*)(arows + mrow*136 + c*32 + (q<<3));
#pragma unroll
      for (int ntl = 0; ntl < 4; ntl++){
        short8 bf = *(const short8*)(wbuf + c*4096 + (ntb+ntl)*512 + loff);
        acc[ntl] = __builtin_amdgcn_mfma_f32_16x16x32_f16(a, bf, acc[ntl], 0, 0, 0);
      }
    }
  };

  // ---------------- init: positions, distances, cached A-frags, x init ----------------
  short8 aS[8], aA[8];
  float dN[4];
  {
    float* rs = (float*)zst;            // overlay (dead until zpass(0))
    float* Rs = rs + 256;
    if (tid < 64){
#pragma unroll
      for (int k = 0; k < 3; k++) rs[tid*4+k] = r_g[(b*64+tid)*3 + k];
    } else if (tid < 80){
      int n = tid - 64;
#pragma unroll
      for (int k = 0; k < 3; k++) Rs[n*4+k] = R_g[(b*16+n)*3 + k];
    }
    __syncthreads();
    {
      float x0 = rs[mrow*4], x1 = rs[mrow*4+1], x2 = rs[mrow*4+2];
#pragma unroll
      for (int c = 0; c < 8; c++){
        int j = 32*sp + 4*c + q;
        float dx = x0-rs[j*4], dy = x1-rs[j*4+1], dz = x2-rs[j*4+2];
        float dd = sqrtf(dx*dx + dy*dy + dz*dz + 1e-12f);
        aS[c] = rbf8(dd);
        if (j == mrow) aS[c] = (short8)0;        // no self-interaction
        j = 32*(1-sp) + 4*c + q;
        dx = x0-rs[j*4]; dy = x1-rs[j*4+1]; dz = x2-rs[j*4+2];
        aA[c] = rbf8(sqrtf(dx*dx + dy*dy + dz*dz + 1e-12f));
      }
#pragma unroll
      for (int c = 0; c < 4; c++){
        int n = 4*c + q;
        float dx = x0-Rs[n*4], dy = x1-Rs[n*4+1], dz = x2-Rs[n*4+2];
        dN[c] = sqrtf(dx*dx + dy*dy + dz*dz + 1e-12f);
      }
    }
    {
      int i = tid >> 3, nb = (tid & 7)*2;
      float y0 = rs[i*4], y1 = rs[i*4+1], y2 = rs[i*4+2];
#pragma unroll
      for (int nn = 0; nn < 2; nn++){
        int n = nb + nn;
        float dx = y0-Rs[n*4], dy = y1-Rs[n*4+1], dz = y2-Rs[n*4+2];
        float dd = sqrtf(dx*dx + dy*dy + dz*dz + 1e-12f);
        *(short8*)&xb[i*136 + n*8] = rbf8(dd);
      }
    }
    stg_ld(wsegs + 0);          // L0.W0
    stg_st();
    __syncthreads();            // wbuf + xb visible
    stg_ld(wsegs + 16384);      // prefetch L0.W1
  }

  f32x4 xr[4];
#pragma unroll
  for (int ntl = 0; ntl < 4; ntl++)
#pragma unroll
    for (int rr = 0; rr < 4; rr++)
      xr[ntl][rr] = h2f(xb[(i0 + q*4 + rr)*136 + (ntb+ntl)*16 + col]);

  const f32x4 vzero = {0.f, 0.f, 0.f, 0.f};

#pragma unroll 1
  for (int l = 0; l < 3; l++){
    const u16* slab = wsegs + l*81920;
    float bupr[4];
#pragma unroll
    for (int ntl = 0; ntl < 4; ntl++) bupr[ntl] = bup_g[l*128 + (ntb+ntl)*16 + col];

    f32x4 upd[4];
#pragma unroll
    for (int ntl = 0; ntl < 4; ntl++) upd[ntl] = vzero;

    auto zpass = [&](int pass){
      const float* weX = pass ? weA_g : weS_g;
      const int jb0 = pass ? 32*(1-sp) : 32*sp;
      const short8* aF = pass ? aA : aS;
      f32x4 zacc[4];
#pragma unroll
      for (int ntl = 0; ntl < 4; ntl++) zacc[ntl] = vzero;
#pragma unroll
      for (int ntl = 0; ntl < 4; ntl++){
        int nt = ntb + ntl;
        h2 wp[4];
#pragma unroll
        for (int p = 0; p < 4; p++){
          h2 t;
          t[0] = (_Float16)weX[(l*8 + 2*p  )*128 + nt*16 + col];
          t[1] = (_Float16)weX[(l*8 + 2*p+1)*128 + nt*16 + col];
          wp[p] = t;
        }
        u16 xv[8];
#pragma unroll
        for (int c = 0; c < 8; c++) xv[c] = xb[(jb0 + 4*c + q)*136 + nt*16 + col];
#pragma unroll
        for (int c = 0; c < 8; c++){
          _Float16 xh = __builtin_bit_cast(_Float16, xv[c]);
          h2 xd; xd[0] = xh; xd[1] = xh;
          u32x4 bu;
#pragma unroll
          for (int p = 0; p < 4; p++)
            bu[p] = __builtin_bit_cast(u32, (h2)(xd * wp[p]));
          short8 bf = __builtin_bit_cast(short8, bu);
          zacc[ntl] = __builtin_amdgcn_mfma_f32_16x16x32_f16(aF[c], bf, zacc[ntl], 0, 0, 0);
        }
      }
#pragma unroll
      for (int ntl = 0; ntl < 4; ntl++)
#pragma unroll
        for (int rr = 0; rr < 4; rr++)
          zst[(i0 + q*4 + rr)*136 + (ntb+ntl)*16 + col] = f2h(zacc[ntl][rr]);
    };

    // ---- t0: zpass(0)->zst | x@W0 | [st W1, ld Y]
    zpass(0);
    gemm4(xb, upd);
    __syncthreads(); stg_st(); stg_ld(slab + 4*16384); __syncthreads();
    // ---- t1: zs@W1 | [st Y, ld W2]
    gemm4(zst, upd);
    __syncthreads(); stg_st(); stg_ld(slab + 2*16384); __syncthreads();
    // ---- t2: zpass(1)->zst | zn acc @ Y | [st W2, ld W3]
    zpass(1);
    f32x4 zn[4];
#pragma unroll
    for (int ntl = 0; ntl < 4; ntl++) zn[ntl] = vzero;
#pragma unroll
    for (int c = 0; c < 4; c++){
      short8 a = rbf8(dN[c]);
#pragma unroll
      for (int ntl = 0; ntl < 4; ntl++){
        short8 bf = *(const short8*)(wbuf + c*4096 + (ntb+ntl)*512 + loff);
        zn[ntl] = __builtin_amdgcn_mfma_f32_16x16x32_f16(a, bf, zn[ntl], 0, 0, 0);
      }
    }
    __syncthreads(); stg_st(); stg_ld(slab + 3*16384); __syncthreads();
    // ---- t3: za@W2 | [st W3, ld next W0]
    gemm4(zst, upd);
    __syncthreads(); stg_st();
    if (l < 2) stg_ld(slab + 81920);
    __syncthreads();
    // ---- t4: zn->zst ; sync ; zn@W3 | epilogue | [st W0', ld W1']
#pragma unroll
    for (int ntl = 0; ntl < 4; ntl++)
#pragma unroll
      for (int rr = 0; rr < 4; rr++)
        zst[(i0 + q*4 + rr)*136 + (ntb+ntl)*16 + col] = f2h(zn[ntl][rr]);
    __syncthreads();
    gemm4(zst, upd);
#pragma unroll
    for (int ntl = 0; ntl < 4; ntl++){
#pragma unroll
      for (int rr = 0; rr < 4; rr++){
        float v = upd[ntl][rr] + bupr[ntl];
        float e = __expf(2.0f * v);
        float th = 1.0f - 2.0f * __builtin_amdgcn_rcpf(e + 1.0f);
        xr[ntl][rr] += th;
      }
    }
    if (l < 2){
#pragma unroll
      for (int ntl = 0; ntl < 4; ntl++)
#pragma unroll
        for (int rr = 0; rr < 4; rr++)
          xb[(i0 + q*4 + rr)*136 + (ntb+ntl)*16 + col] = f2h(xr[ntl][rr]);
      __syncthreads(); stg_st(); stg_ld(slab + 81920 + 16384); __syncthreads();
    } else {
#pragma unroll
      for (int ntl = 0; ntl < 4; ntl++)
#pragma unroll
        for (int rr = 0; rr < 4; rr++)
          out[(b*64 + i0 + q*4 + rr)*128 + (ntb+ntl)*16 + col] = xr[ntl][rr];
    }
  }
}

extern "C" void kernel_launch(void* const* d_in, const int* in_sizes, int n_in,
                              void* d_out, int out_size, void* d_ws, size_t ws_size,
                              hipStream_t stream){
  const float* r     = (const float*)d_in[0];
  const float* R     = (const float*)d_in[1];
  const float* embed = (const float*)d_in[2];
  const float* weS   = (const float*)d_in[3];
  const float* weA   = (const float*)d_in[4];
  const float* weN   = (const float*)d_in[5];
  const float* wup   = (const float*)d_in[6];
  const float* bup   = (const float*)d_in[7];
  const int* atyp    = (const int*)d_in[8];

  u16* wsegs = (u16*)d_ws;                // 3*5*16384 fp16 = 491,520 B (proven size)

  (void)hipFuncSetAttribute((const void*)gnn_main,
                            hipFuncAttributeMaxDynamicSharedMemorySize, 67584);
  gnn_prep<<<15, 256, 0, stream>>>(wup, weN, embed, atyp, wsegs);
  gnn_main<<<512, 512, 67584, stream>>>(r, R, weS, weA, bup, wsegs, (float*)d_out);
}

// Round 10
// 184.985 us; speedup vs baseline: 1.1105x; 1.1105x over previous
//
#include <hip/hip_runtime.h>

// ElectronGNN on MI355X (gfx950).  Inputs float32, output float32.
// Round 10: r9 design with register fixes -> real 16 waves/CU.
//   512 blocks x 512 threads, 1 batch/block, 2 blocks/CU (LDS 67,584 B).
//   8 waves = 4 row-tiles x 2 N-halves; each wave: 16 rows x 64 cols.
//   __launch_bounds__(512,2): 2nd arg is min BLOCKS/CU (CUDA semantics —
//   r9's (512,4) forced VGPR=64 and spilled 448 MB to scratch).
//   No aS/aA frag cache (r8: neutral); distances in regs, rbf8 recomputed
//   per chunk (r7-proven), zpass c-outer/nt-inner to cap live regs ~128.
// Single 32KB weight buffer, reg-prefetch one seg ahead (r9 schedule).
// z B-frags: per-lane v_pk_mul_f16 recompute.  zst pair-shared: every
// write->read crosses a barrier (audited).  d_ws: 491,520 B (r7-proven).

typedef unsigned short u16;
typedef unsigned int u32;
typedef __attribute__((ext_vector_type(8))) short short8;
typedef __attribute__((ext_vector_type(4))) float f32x4;
typedef __attribute__((ext_vector_type(4))) u32 u32x4;
typedef _Float16 h2 __attribute__((ext_vector_type(2)));

__device__ __forceinline__ u16 f2h(float f){ return __builtin_bit_cast(u16, (_Float16)f); }
__device__ __forceinline__ float h2f(u16 a){ return (float)__builtin_bit_cast(_Float16, a); }

__device__ __forceinline__ short8 rbf8(float dd){
  short8 a;
#pragma unroll
  for (int f = 0; f < 8; f++){
    float u = dd - (4.0f/7.0f)*(float)f;
    a[f] = (short)f2h(__expf(-u*u));
  }
  return a;
}

// ---------------- prep: frag-linear weight slabs (r7-proven, unchanged) ----------------
__global__ __launch_bounds__(256) void gnn_prep(
    const float* __restrict__ w_up, const float* __restrict__ we_ne,
    const float* __restrict__ embed, const int* __restrict__ atypes,
    u16* __restrict__ wsegs){
  __shared__ u16 lw[16384];
  const int blk = blockIdx.x;          // l*5 + seg
  const int l = blk / 5, seg = blk % 5;
  const int tid = threadIdx.x;
  if (seg < 4){
    const float* src = w_up + (l*512 + seg*128)*128;
#pragma unroll
    for (int mm = 0; mm < 16; mm++){
      int idx = mm*1024 + tid*4;
      float4 v = *(const float4*)(src + idx);
      lw[idx+0] = f2h(v.x); lw[idx+1] = f2h(v.y);
      lw[idx+2] = f2h(v.z); lw[idx+3] = f2h(v.w);
    }
  } else {
#pragma unroll
    for (int mm = 0; mm < 16; mm++){
      int idx = mm*1024 + tid*4;
      int k = idx >> 7, dout = idx & 127;
      int n = k >> 3, f = k & 7;
      float4 ye = *(const float4*)(embed + atypes[n]*128 + dout);
      float4 wn = *(const float4*)(we_ne + (l*8 + f)*128 + dout);
      lw[idx+0] = f2h(ye.x*wn.x); lw[idx+1] = f2h(ye.y*wn.y);
      lw[idx+2] = f2h(ye.z*wn.z); lw[idx+3] = f2h(ye.w*wn.w);
    }
  }
  __syncthreads();
  u16* dst = wsegs + blk*16384;
  const int col = tid & 15, q = (tid >> 4) & 3;
#pragma unroll
  for (int m = 0; m < 8; m++){
    int slot = m*4 + (tid >> 6);
    int c = slot >> 3, nt = slot & 7;
    int kbase = c*32 + q*8;
    int dout = nt*16 + col;
    short8 vv;
#pragma unroll
    for (int jj = 0; jj < 8; jj++) vv[jj] = (short)lw[(kbase+jj)*128 + dout];
    *(short8*)(dst + m*2048 + tid*8) = vv;
  }
}

// ---------------- main ----------------
__global__ __launch_bounds__(512, 2) void gnn_main(
    const float* __restrict__ r_g, const float* __restrict__ R_g,
    const float* __restrict__ weS_g, const float* __restrict__ weA_g,
    const float* __restrict__ bup_g,
    const u16* __restrict__ wsegs,
    float* __restrict__ out)
{
  extern __shared__ __attribute__((aligned(16))) u16 lds[];
  u16* const wbuf = lds;                 // 16384 u16 (32 KB)
  u16* const xb   = lds + 16384;         // [64][136]
  u16* const zst  = lds + 16384 + 8704;  // [64][136]

  const int tid  = threadIdx.x;
  const int b    = blockIdx.x;
  const int lane = tid & 63;
  const int w    = tid >> 6;            // 0..7
  const int wq   = w & 3;               // row tile
  const int nh   = w >> 2;              // N half 0/1
  const int col  = lane & 15;
  const int q    = lane >> 4;
  const int i0   = wq * 16;
  const int sp   = wq >> 1;
  const int mrow = i0 + col;
  const int loff = (q*16 + col) * 8;
  const int ntb  = nh * 4;              // nt base for this wave

  u32x4 stg[4];
  auto stg_ld = [&](const u16* src){
#pragma unroll
    for (int m = 0; m < 4; m++) stg[m] = *(const u32x4*)(src + m*4096 + tid*8);
  };
  auto stg_st = [&](){
#pragma unroll
    for (int m = 0; m < 4; m++) *(u32x4*)(wbuf + m*4096 + tid*8) = stg[m];
  };
  auto gemm4 = [&](const u16* arows, f32x4* acc){
#pragma unroll
    for (int c = 0; c < 4; c++){
      short8 a = *(const short8*)(arows + mrow*136 + c*32 + (q<<3));
#pragma unroll
      for (int ntl = 0; ntl < 4; ntl++){
        short8 bf = *(const short8*)(wbuf + c*4096 + (ntb+ntl)*512 + loff);
        acc[ntl] = __builtin_amdgcn_mfma_f32_16x16x32_f16(a, bf, acc[ntl], 0, 0, 0);
      }
    }
  };

  // ---------------- init: positions, distances (regs), x init ----------------
  float dS[8], dA[8], dN[4];
  {
    float* rs = (float*)zst;            // overlay (dead until zpass(0))
    float* Rs = rs + 256;
    if (tid < 64){
#pragma unroll
      for (int k = 0; k < 3; k++) rs[tid*4+k] = r_g[(b*64+tid)*3 + k];
    } else if (tid < 80){
      int n = tid - 64;
#pragma unroll
      for (int k = 0; k < 3; k++) Rs[n*4+k] = R_g[(b*16+n)*3 + k];
    }
    __syncthreads();
    {
      float x0 = rs[mrow*4], x1 = rs[mrow*4+1], x2 = rs[mrow*4+2];
#pragma unroll
      for (int c = 0; c < 8; c++){
        int j = 32*sp + 4*c + q;
        float dx = x0-rs[j*4], dy = x1-rs[j*4+1], dz = x2-rs[j*4+2];
        dS[c] = sqrtf(dx*dx + dy*dy + dz*dz + 1e-12f);
        j = 32*(1-sp) + 4*c + q;
        dx = x0-rs[j*4]; dy = x1-rs[j*4+1]; dz = x2-rs[j*4+2];
        dA[c] = sqrtf(dx*dx + dy*dy + dz*dz + 1e-12f);
      }
#pragma unroll
      for (int c = 0; c < 4; c++){
        int n = 4*c + q;
        float dx = x0-Rs[n*4], dy = x1-Rs[n*4+1], dz = x2-Rs[n*4+2];
        dN[c] = sqrtf(dx*dx + dy*dy + dz*dz + 1e-12f);
      }
    }
    {
      int i = tid >> 3, nb = (tid & 7)*2;
      float y0 = rs[i*4], y1 = rs[i*4+1], y2 = rs[i*4+2];
#pragma unroll
      for (int nn = 0; nn < 2; nn++){
        int n = nb + nn;
        float dx = y0-Rs[n*4], dy = y1-Rs[n*4+1], dz = y2-Rs[n*4+2];
        float dd = sqrtf(dx*dx + dy*dy + dz*dz + 1e-12f);
        *(short8*)&xb[i*136 + n*8] = rbf8(dd);
      }
    }
    stg_ld(wsegs + 0);          // L0.W0
    stg_st();
    __syncthreads();            // wbuf + xb visible
    stg_ld(wsegs + 16384);      // prefetch L0.W1
  }

  f32x4 xr[4];
#pragma unroll
  for (int ntl = 0; ntl < 4; ntl++)
#pragma unroll
    for (int rr = 0; rr < 4; rr++)
      xr[ntl][rr] = h2f(xb[(i0 + q*4 + rr)*136 + (ntb+ntl)*16 + col]);

  const f32x4 vzero = {0.f, 0.f, 0.f, 0.f};

#pragma unroll 1
  for (int l = 0; l < 3; l++){
    const u16* slab = wsegs + l*81920;
    float bupr[4];
#pragma unroll
    for (int ntl = 0; ntl < 4; ntl++) bupr[ntl] = bup_g[l*128 + (ntb+ntl)*16 + col];

    f32x4 upd[4];
#pragma unroll
    for (int ntl = 0; ntl < 4; ntl++) upd[ntl] = vzero;

    // z-pass: c-outer (rbf8 per chunk), nt-inner; wp hoisted (16 regs)
    auto zpass = [&](int pass){
      const float* weX = pass ? weA_g : weS_g;
      const int jb0 = pass ? 32*(1-sp) : 32*sp;
      const float* dX = pass ? dA : dS;
      h2 wp[4][4];
#pragma unroll
      for (int ntl = 0; ntl < 4; ntl++){
        int nt = ntb + ntl;
#pragma unroll
        for (int p = 0; p < 4; p++){
          h2 t;
          t[0] = (_Float16)weX[(l*8 + 2*p  )*128 + nt*16 + col];
          t[1] = (_Float16)weX[(l*8 + 2*p+1)*128 + nt*16 + col];
          wp[ntl][p] = t;
        }
      }
      f32x4 zacc[4];
#pragma unroll
      for (int ntl = 0; ntl < 4; ntl++) zacc[ntl] = vzero;
#pragma unroll
      for (int c = 0; c < 8; c++){
        int j = jb0 + 4*c + q;
        short8 aF = rbf8(dX[c]);
        if (!pass && j == mrow) aF = (short8)0;     // no self-interaction
#pragma unroll
        for (int ntl = 0; ntl < 4; ntl++){
          _Float16 xh = __builtin_bit_cast(_Float16, xb[j*136 + (ntb+ntl)*16 + col]);
          h2 xd; xd[0] = xh; xd[1] = xh;
          u32x4 bu;
#pragma unroll
          for (int p = 0; p < 4; p++)
            bu[p] = __builtin_bit_cast(u32, (h2)(xd * wp[ntl][p]));
          short8 bf = __builtin_bit_cast(short8, bu);
          zacc[ntl] = __builtin_amdgcn_mfma_f32_16x16x32_f16(aF, bf, zacc[ntl], 0, 0, 0);
        }
      }
#pragma unroll
      for (int ntl = 0; ntl < 4; ntl++)
#pragma unroll
        for (int rr = 0; rr < 4; rr++)
          zst[(i0 + q*4 + rr)*136 + (ntb+ntl)*16 + col] = f2h(zacc[ntl][rr]);
    };

    // ---- t0: zpass(0)->zst | x@W0 | [st W1, ld Y]
    zpass(0);
    gemm4(xb, upd);
    __syncthreads(); stg_st(); stg_ld(slab + 4*16384); __syncthreads();
    // ---- t1: zs@W1 | [st Y, ld W2]
    gemm4(zst, upd);
    __syncthreads(); stg_st(); stg_ld(slab + 2*16384); __syncthreads();
    // ---- t2: zpass(1)->zst | zn acc @ Y | [st W2, ld W3]
    zpass(1);
    f32x4 zn[4];
#pragma unroll
    for (int ntl = 0; ntl < 4; ntl++) zn[ntl] = vzero;
#pragma unroll
    for (int c = 0; c < 4; c++){
      short8 a = rbf8(dN[c]);
#pragma unroll
      for (int ntl = 0; ntl < 4; ntl++){
        short8 bf = *(const short8*)(wbuf + c*4096 + (ntb+ntl)*512 + loff);
        zn[ntl] = __builtin_amdgcn_mfma_f32_16x16x32_f16(a, bf, zn[ntl], 0, 0, 0);
      }
    }
    __syncthreads(); stg_st(); stg_ld(slab + 3*16384); __syncthreads();
    // ---- t3: za@W2 | [st W3, ld next W0]
    gemm4(zst, upd);
    __syncthreads(); stg_st();
    if (l < 2) stg_ld(slab + 81920);
    __syncthreads();
    // ---- t4: zn->zst ; sync ; zn@W3 | epilogue | [st W0', ld W1']
#pragma unroll
    for (int ntl = 0; ntl < 4; ntl++)
#pragma unroll
      for (int rr = 0; rr < 4; rr++)
        zst[(i0 + q*4 + rr)*136 + (ntb+ntl)*16 + col] = f2h(zn[ntl][rr]);
    __syncthreads();
    gemm4(zst, upd);
#pragma unroll
    for (int ntl = 0; ntl < 4; ntl++){
#pragma unroll
      for (int rr = 0; rr < 4; rr++){
        float v = upd[ntl][rr] + bupr[ntl];
        float e = __expf(2.0f * v);
        float th = 1.0f - 2.0f * __builtin_amdgcn_rcpf(e + 1.0f);
        xr[ntl][rr] += th;
      }
    }
    if (l < 2){
#pragma unroll
      for (int ntl = 0; ntl < 4; ntl++)
#pragma unroll
        for (int rr = 0; rr < 4; rr++)
          xb[(i0 + q*4 + rr)*136 + (ntb+ntl)*16 + col] = f2h(xr[ntl][rr]);
      __syncthreads(); stg_st(); stg_ld(slab + 81920 + 16384); __syncthreads();
    } else {
#pragma unroll
      for (int ntl = 0; ntl < 4; ntl++)
#pragma unroll
        for (int rr = 0; rr < 4; rr++)
          out[(b*64 + i0 + q*4 + rr)*128 + (ntb+ntl)*16 + col] = xr[ntl][rr];
    }
  }
}

extern "C" void kernel_launch(void* const* d_in, const int* in_sizes, int n_in,
                              void* d_out, int out_size, void* d_ws, size_t ws_size,
                              hipStream_t stream){
  const float* r     = (const float*)d_in[0];
  const float* R     = (const float*)d_in[1];
  const float* embed = (const float*)d_in[2];
  const float* weS   = (const float*)d_in[3];
  const float* weA   = (const float*)d_in[4];
  const float* weN   = (const float*)d_in[5];
  const float* wup   = (const float*)d_in[6];
  const float* bup   = (const float*)d_in[7];
  const int* atyp    = (const int*)d_in[8];

  u16* wsegs = (u16*)d_ws;                // 3*5*16384 fp16 = 491,520 B (proven size)

  (void)hipFuncSetAttribute((const void*)gnn_main,
                            hipFuncAttributeMaxDynamicSharedMemorySize, 67584);
  gnn_prep<<<15, 256, 0, stream>>>(wup, weN, embed, atyp, wsegs);
  gnn_main<<<512, 512, 67584, stream>>>(r, R, weS, weA, bup, wsegs, (float*)d_out);
}

// Round 11
// 155.944 us; speedup vs baseline: 1.3174x; 1.1862x over previous
//
#include <hip/hip_runtime.h>

// ElectronGNN on MI355X (gfx950).  Inputs float32, output float32.
// Round 11: LDS-pressure attack.  Weight GEMMs on v_mfma_f32_32x32x16_f16
// (2x FLOP per B-frag byte -> B-reads /4); zpass/zn keep the proven 16x16 path
// with cached rbf8 A-frags (aS/aA/aN).  512 blocks x 512 threads, 8 waves/CU,
// __launch_bounds__(512,1): 256-reg cap, no spill (r10's (512,2) spilled 83MB).
// GEMM wave map: 2 M-halves x 4 N-quarters (32x32 tile); z-phase map unchanged
// (4 row-tiles x 2 N-halves).  Single 32KB weight buffer, reg-prefetch one seg
// ahead, r10 barrier schedule verbatim (all zst/xb hazards cross barriers).
// Prep emits segs 0-3 in 32x32-frag-linear order, seg 4 (Y) in 16x16 order.
// d_ws: 491,520 B (r7-proven).

typedef unsigned short u16;
typedef unsigned int u32;
typedef __attribute__((ext_vector_type(8))) short short8;
typedef __attribute__((ext_vector_type(4))) float f32x4;
typedef __attribute__((ext_vector_type(16))) float f32x16;
typedef __attribute__((ext_vector_type(4))) u32 u32x4;
typedef _Float16 h2 __attribute__((ext_vector_type(2)));

__device__ __forceinline__ u16 f2h(float f){ return __builtin_bit_cast(u16, (_Float16)f); }
__device__ __forceinline__ float h2f(u16 a){ return (float)__builtin_bit_cast(_Float16, a); }

__device__ __forceinline__ short8 rbf8(float dd){
  short8 a;
#pragma unroll
  for (int f = 0; f < 8; f++){
    float u = dd - (4.0f/7.0f)*(float)f;
    a[f] = (short)f2h(__expf(-u*u));
  }
  return a;
}

// ---------------- prep: frag-linear weight slabs ----------------
// segs 0..3 (w_up quarters): 32x32-frag order
//   dst[kc*2048 + nq*512 + lane*8 + jj] = W[kc*16 + (lane>>5)*8 + jj][nq*32 + (lane&31)]
// seg 4 (Y = y*we_ne): 16x16-frag order (r7-proven)
__global__ __launch_bounds__(256) void gnn_prep(
    const float* __restrict__ w_up, const float* __restrict__ we_ne,
    const float* __restrict__ embed, const int* __restrict__ atypes,
    u16* __restrict__ wsegs){
  __shared__ u16 lw[16384];            // [k][dout] k-major
  const int blk = blockIdx.x;          // l*5 + seg
  const int l = blk / 5, seg = blk % 5;
  const int tid = threadIdx.x;
  if (seg < 4){
    const float* src = w_up + (l*512 + seg*128)*128;
#pragma unroll
    for (int mm = 0; mm < 16; mm++){
      int idx = mm*1024 + tid*4;
      float4 v = *(const float4*)(src + idx);
      lw[idx+0] = f2h(v.x); lw[idx+1] = f2h(v.y);
      lw[idx+2] = f2h(v.z); lw[idx+3] = f2h(v.w);
    }
  } else {
#pragma unroll
    for (int mm = 0; mm < 16; mm++){
      int idx = mm*1024 + tid*4;
      int k = idx >> 7, dout = idx & 127;
      int n = k >> 3, f = k & 7;
      float4 ye = *(const float4*)(embed + atypes[n]*128 + dout);
      float4 wn = *(const float4*)(we_ne + (l*8 + f)*128 + dout);
      lw[idx+0] = f2h(ye.x*wn.x); lw[idx+1] = f2h(ye.y*wn.y);
      lw[idx+2] = f2h(ye.z*wn.z); lw[idx+3] = f2h(ye.w*wn.w);
    }
  }
  __syncthreads();
  u16* dst = wsegs + blk*16384;
  if (seg < 4){
    const int ls5 = (tid >> 5) & 1, l31 = tid & 31, nq = tid >> 6;
#pragma unroll
    for (int m = 0; m < 8; m++){          // m == kc
      short8 vv;
#pragma unroll
      for (int jj = 0; jj < 8; jj++)
        vv[jj] = (short)lw[(m*16 + ls5*8 + jj)*128 + nq*32 + l31];
      *(short8*)(dst + m*2048 + tid*8) = vv;
    }
  } else {
    const int col = tid & 15, q = (tid >> 4) & 3;
#pragma unroll
    for (int m = 0; m < 8; m++){
      int slot = m*4 + (tid >> 6);
      int c = slot >> 3, nt = slot & 7;
      int kbase = c*32 + q*8;
      int dout = nt*16 + col;
      short8 vv;
#pragma unroll
      for (int jj = 0; jj < 8; jj++) vv[jj] = (short)lw[(kbase+jj)*128 + dout];
      *(short8*)(dst + m*2048 + tid*8) = vv;
    }
  }
}

// ---------------- main ----------------
__global__ __launch_bounds__(512, 1) void gnn_main(
    const float* __restrict__ r_g, const float* __restrict__ R_g,
    const float* __restrict__ weS_g, const float* __restrict__ weA_g,
    const float* __restrict__ bup_g,
    const u16* __restrict__ wsegs,
    float* __restrict__ out)
{
  extern __shared__ __attribute__((aligned(16))) u16 lds[];
  u16* const wbuf = lds;                 // 16384 u16 (32 KB)
  u16* const xb   = lds + 16384;         // [64][136]
  u16* const zst  = lds + 16384 + 8704;  // [64][136]

  const int tid  = threadIdx.x;
  const int b    = blockIdx.x;
  const int lane = tid & 63;
  const int w    = tid >> 6;            // 0..7
  // z-phase mapping (16x16, r7/r8-proven)
  const int wq   = w & 3;               // row tile
  const int nh   = w >> 2;              // N half
  const int col  = lane & 15;
  const int q    = lane >> 4;
  const int i0   = wq * 16;
  const int sp   = wq >> 1;
  const int mrow = i0 + col;
  const int loff = (q*16 + col) * 8;
  const int ntb  = nh * 4;
  // gemm32 mapping
  const int mh   = w & 1;               // M half (32 rows)
  const int nq   = w >> 1;              // N quarter (32 cols)
  const int l31  = lane & 31;
  const int ls5  = (lane >> 5) & 1;
  const int aoff = (32*mh + l31)*136;   // A row base (u16)
  const int boff = nq*512 + lane*8;     // B frag base within kc chunk
  const int dcol = 32*nq + l31;         // this lane's output column

  u32x4 stg[4];
  auto stg_ld = [&](const u16* src){
#pragma unroll
    for (int m = 0; m < 4; m++) stg[m] = *(const u32x4*)(src + m*4096 + tid*8);
  };
  auto stg_st = [&](){
#pragma unroll
    for (int m = 0; m < 4; m++) *(u32x4*)(wbuf + m*4096 + tid*8) = stg[m];
  };
  // 32x32x16 GEMM over one K=128 seg: 8 kc chunks, wave tile 32x32
  auto gemm32 = [&](const u16* arows, f32x16& acc){
#pragma unroll
    for (int kc = 0; kc < 8; kc++){
      short8 a  = *(const short8*)(arows + aoff + kc*16 + ls5*8);
      short8 bf = *(const short8*)(wbuf + kc*2048 + boff);
      acc = __builtin_amdgcn_mfma_f32_32x32x16_f16(a, bf, acc, 0, 0, 0);
    }
  };

  // ---------------- init: positions, cached A-frags, x init ----------------
  short8 aS[8], aA[8], aN[4];
  {
    float* rs = (float*)zst;            // overlay (dead until zpass(0))
    float* Rs = rs + 256;
    if (tid < 64){
#pragma unroll
      for (int k = 0; k < 3; k++) rs[tid*4+k] = r_g[(b*64+tid)*3 + k];
    } else if (tid < 80){
      int n = tid - 64;
#pragma unroll
      for (int k = 0; k < 3; k++) Rs[n*4+k] = R_g[(b*16+n)*3 + k];
    }
    __syncthreads();
    {
      float x0 = rs[mrow*4], x1 = rs[mrow*4+1], x2 = rs[mrow*4+2];
#pragma unroll
      for (int c = 0; c < 8; c++){
        int j = 32*sp + 4*c + q;
        float dx = x0-rs[j*4], dy = x1-rs[j*4+1], dz = x2-rs[j*4+2];
        aS[c] = rbf8(sqrtf(dx*dx + dy*dy + dz*dz + 1e-12f));
        if (j == mrow) aS[c] = (short8)0;        // no self-interaction
        j = 32*(1-sp) + 4*c + q;
        dx = x0-rs[j*4]; dy = x1-rs[j*4+1]; dz = x2-rs[j*4+2];
        aA[c] = rbf8(sqrtf(dx*dx + dy*dy + dz*dz + 1e-12f));
      }
#pragma unroll
      for (int c = 0; c < 4; c++){
        int n = 4*c + q;
        float dx = x0-Rs[n*4], dy = x1-Rs[n*4+1], dz = x2-Rs[n*4+2];
        aN[c] = rbf8(sqrtf(dx*dx + dy*dy + dz*dz + 1e-12f));
      }
    }
    {
      int i = tid >> 3, nb = (tid & 7)*2;
      float y0 = rs[i*4], y1 = rs[i*4+1], y2 = rs[i*4+2];
#pragma unroll
      for (int nn = 0; nn < 2; nn++){
        int n = nb + nn;
        float dx = y0-Rs[n*4], dy = y1-Rs[n*4+1], dz = y2-Rs[n*4+2];
        float dd = sqrtf(dx*dx + dy*dy + dz*dz + 1e-12f);
        *(short8*)&xb[i*136 + n*8] = rbf8(dd);
      }
    }
    stg_ld(wsegs + 0);          // L0.W0
    stg_st();
    __syncthreads();            // wbuf + xb visible
    stg_ld(wsegs + 16384);      // prefetch L0.W1
  }

  // x residual fp32 in 32x32 C-layout: row 32mh+(reg&3)+8*(reg>>2)+4*ls5, col dcol
  f32x16 xr;
#pragma unroll
  for (int reg = 0; reg < 16; reg++){
    int il = (reg&3) + 8*(reg>>2) + 4*ls5;
    xr[reg] = h2f(xb[(32*mh + il)*136 + dcol]);
  }

#pragma unroll 1
  for (int l = 0; l < 3; l++){
    const u16* slab = wsegs + l*81920;
    const float bupr = bup_g[l*128 + dcol];

    f32x16 upd = (f32x16)0.f;

    auto zpass = [&](int pass){
      const float* weX = pass ? weA_g : weS_g;
      const int jb0 = pass ? 32*(1-sp) : 32*sp;
      h2 wp[4][4];
#pragma unroll
      for (int ntl = 0; ntl < 4; ntl++){
        int nt = ntb + ntl;
#pragma unroll
        for (int p = 0; p < 4; p++){
          h2 t;
          t[0] = (_Float16)weX[(l*8 + 2*p  )*128 + nt*16 + col];
          t[1] = (_Float16)weX[(l*8 + 2*p+1)*128 + nt*16 + col];
          wp[ntl][p] = t;
        }
      }
      f32x4 zacc[4];
#pragma unroll
      for (int ntl = 0; ntl < 4; ntl++) zacc[ntl] = (f32x4)0.f;
#pragma unroll
      for (int c = 0; c < 8; c++){
        int j = jb0 + 4*c + q;
        short8 aF = pass ? aA[c] : aS[c];
#pragma unroll
        for (int ntl = 0; ntl < 4; ntl++){
          _Float16 xh = __builtin_bit_cast(_Float16, xb[j*136 + (ntb+ntl)*16 + col]);
          h2 xd; xd[0] = xh; xd[1] = xh;
          u32x4 bu;
#pragma unroll
          for (int p = 0; p < 4; p++)
            bu[p] = __builtin_bit_cast(u32, (h2)(xd * wp[ntl][p]));
          short8 bf = __builtin_bit_cast(short8, bu);
          zacc[ntl] = __builtin_amdgcn_mfma_f32_16x16x32_f16(aF, bf, zacc[ntl], 0, 0, 0);
        }
      }
#pragma unroll
      for (int ntl = 0; ntl < 4; ntl++)
#pragma unroll
        for (int rr = 0; rr < 4; rr++)
          zst[(i0 + q*4 + rr)*136 + (ntb+ntl)*16 + col] = f2h(zacc[ntl][rr]);
    };

    // ---- t0: zpass(0)->zst | x@W0 (32x32) | [st W1, ld Y]
    zpass(0);
    gemm32(xb, upd);
    __syncthreads(); stg_st(); stg_ld(slab + 4*16384); __syncthreads();
    // ---- t1: zs@W1 | [st Y, ld W2]
    gemm32(zst, upd);
    __syncthreads(); stg_st(); stg_ld(slab + 2*16384); __syncthreads();
    // ---- t2: zpass(1)->zst | zn acc @ Y (16x16) | [st W2, ld W3]
    zpass(1);
    f32x4 zn[4];
#pragma unroll
    for (int ntl = 0; ntl < 4; ntl++) zn[ntl] = (f32x4)0.f;
#pragma unroll
    for (int c = 0; c < 4; c++){
#pragma unroll
      for (int ntl = 0; ntl < 4; ntl++){
        short8 bf = *(const short8*)(wbuf + c*4096 + (ntb+ntl)*512 + loff);
        zn[ntl] = __builtin_amdgcn_mfma_f32_16x16x32_f16(aN[c], bf, zn[ntl], 0, 0, 0);
      }
    }
    __syncthreads(); stg_st(); stg_ld(slab + 3*16384); __syncthreads();
    // ---- t3: za@W2 | [st W3, ld next W0]
    gemm32(zst, upd);
    __syncthreads(); stg_st();
    if (l < 2) stg_ld(slab + 81920);
    __syncthreads();
    // ---- t4: zn->zst ; sync ; zn@W3 | epilogue | [st W0', ld W1']
#pragma unroll
    for (int ntl = 0; ntl < 4; ntl++)
#pragma unroll
      for (int rr = 0; rr < 4; rr++)
        zst[(i0 + q*4 + rr)*136 + (ntb+ntl)*16 + col] = f2h(zn[ntl][rr]);
    __syncthreads();
    gemm32(zst, upd);
#pragma unroll
    for (int reg = 0; reg < 16; reg++){
      float v = upd[reg] + bupr;
      float e = __expf(2.0f * v);
      float th = 1.0f - 2.0f * __builtin_amdgcn_rcpf(e + 1.0f);
      xr[reg] += th;
    }
    if (l < 2){
#pragma unroll
      for (int reg = 0; reg < 16; reg++){
        int il = (reg&3) + 8*(reg>>2) + 4*ls5;
        xb[(32*mh + il)*136 + dcol] = f2h(xr[reg]);
      }
      __syncthreads(); stg_st(); stg_ld(slab + 81920 + 16384); __syncthreads();
    } else {
#pragma unroll
      for (int reg = 0; reg < 16; reg++){
        int il = (reg&3) + 8*(reg>>2) + 4*ls5;
        out[(b*64 + 32*mh + il)*128 + dcol] = xr[reg];
      }
    }
  }
}

extern "C" void kernel_launch(void* const* d_in, const int* in_sizes, int n_in,
                              void* d_out, int out_size, void* d_ws, size_t ws_size,
                              hipStream_t stream){
  const float* r     = (const float*)d_in[0];
  const float* R     = (const float*)d_in[1];
  const float* embed = (const float*)d_in[2];
  const float* weS   = (const float*)d_in[3];
  const float* weA   = (const float*)d_in[4];
  const float* weN   = (const float*)d_in[5];
  const float* wup   = (const float*)d_in[6];
  const float* bup   = (const float*)d_in[7];
  const int* atyp    = (const int*)d_in[8];

  u16* wsegs = (u16*)d_ws;                // 3*5*16384 fp16 = 491,520 B (proven size)

  (void)hipFuncSetAttribute((const void*)gnn_main,
                            hipFuncAttributeMaxDynamicSharedMemorySize, 67584);
  gnn_prep<<<15, 256, 0, stream>>>(wup, weN, embed, atyp, wsegs);
  gnn_main<<<512, 512, 67584, stream>>>(r, R, weS, weA, bup, wsegs, (float*)d_out);
}